// Round 6
// baseline (1947.241 us; speedup 1.0000x reference)
//
#include <hip/hip_runtime.h>
#include <math.h>

// Problem constants
#define NB   64
#define CIN  64
#define TDIM 256
#define VV   25
#define SS   3
#define COUT 128
#define NTV  (NB * TDIM * VV)              // 409600 elements per channel
#define OUT_TOTAL (NB * COUT * TDIM * VV)  // 52428800
#define TT   8                              // t per block
#define NTILE (TDIM / TT)                   // 32 t-tiles

// Workspace float offsets
#define WS_STATS 0        // 8 copies x (128 sum + 128 sumsq) = 2048 floats
#define WS_AE2   2048     // [25][84]: Aeff[s][v][w] laid out ae[v*84 + s*28 + w]
#define WS_W2    4160     // [24][128]: W2[(s*8+j)*128 + c] = Wg[(s*128+c)*8 + j]
#define WS_BIAS  7232     // [128][28]: bias_eff[c][w]
#define WS_SCALE 10816    // [128]
#define WS_SHIFT 10944    // [128]
#define MID_OFF  16384    // permuted intermediate: [n][t][w][c], 52428800 floats

__device__ __forceinline__ void fma4(float4& a, float s, const float4& b) {
    a.x = fmaf(s, b.x, a.x);
    a.y = fmaf(s, b.y, a.y);
    a.z = fmaf(s, b.z, a.z);
    a.w = fmaf(s, b.w, a.w);
}

// ---------------------------------------------------------------------------
// Prep: build Aeff / W2 / bias_eff tables in ws, zero the stats accumulators.
// ---------------------------------------------------------------------------
__global__ void prep_kernel(const float* __restrict__ A, const float* __restrict__ PA,
                            const float* __restrict__ Wg, const float* __restrict__ bg,
                            float* __restrict__ ws) {
    const int tid = threadIdx.x;
    for (int i = tid; i < 2048; i += 256) ws[WS_STATS + i] = 0.0f;
    for (int i = tid; i < 25 * 84; i += 256) {
        int v = i / 84, r = i % 84;
        int s = r / 28, w = r % 28;
        float val = 0.0f;
        if (w < 25) {
            int idx = s * 625 + v * 25 + w;
            val = A[idx] + PA[idx];
        }
        ws[WS_AE2 + i] = val;
    }
    for (int i = tid; i < 24 * 128; i += 256) {
        int row = i / 128, c = i % 128;
        int s = row / 8, j = row % 8;
        ws[WS_W2 + i] = Wg[(s * 128 + c) * 8 + j];
    }
    for (int i = tid; i < 128 * 28; i += 256) {
        int c = i / 28, w = i % 28;
        float val = 0.0f;
        if (w < 25) {
            for (int s = 0; s < 3; ++s) {
                float cs = 0.0f;
                for (int v = 0; v < 25; ++v) {
                    int idx = s * 625 + v * 25 + w;
                    cs += A[idx] + PA[idx];
                }
                val += bg[s * 128 + c] * cs;
            }
        }
        ws[WS_BIAS + i] = val;
    }
}

// ---------------------------------------------------------------------------
// Main: one block per (n, 8-t tile). Round-3 2-phase schedule, with the
// s_res LDS bounce replaced by register-direct stores to a [n][t][w][c]
// mid layout: thread (ct,wt)'s 4 channels are ADJACENT in c-minor order, so
// each store is a float4 and lanes ct=0..31 cover a dense 512B w-row
// (full-line coverage, incl. w=24). LDS 50.0 KB -> 3 blocks/CU (12 waves).
// Ledger: W2 in LDS (r2); lane-contiguous full-line mid stores only (r1,r4);
// phase-C x-prefetch with phase-local registers only (r1 vs r3).
// ---------------------------------------------------------------------------
template <bool PERM>
__global__ __launch_bounds__(256, 3)
void main_kernel(const float* __restrict__ x, float* __restrict__ ws,
                 float* __restrict__ out, float* __restrict__ mid) {
    __shared__ __align__(16) float s_x[25 * 68];     // xst[v][cin], pad 68
    __shared__ __align__(16) float s_ae[25 * 84];    // ae[v][s*28+w]
    __shared__ __align__(16) float s_w[24 * 128];    // W2[(s*8+j)][c]
    __shared__ __align__(16) float s_y[3 * 64 * 28]; // y[s][cin][w28]
    __shared__ float s_stats[256];                   // 128 sum + 128 sumsq

    const int tid = threadIdx.x;
    const int bid = blockIdx.x;
    const int xcd   = bid & 7;           // dispatch round-robin heuristic
    const int j     = bid >> 3;          // [0,256)
    const int ttile = xcd * 4 + (j & 3); // [0,32): XCD k owns t-tiles [4k,4k+4)
    const int n     = j >> 2;            // [0,64)
    const int t0    = ttile * TT;

    s_stats[tid] = 0.0f;
    for (int i = tid; i < 25 * 84; i += 256) s_ae[i] = ws[WS_AE2 + i];
    for (int i = tid; i < 24 * 128; i += 256) s_w[i] = ws[WS_W2 + i];

    const bool active = tid < 224;
    int c0 = 0, w0 = 0;
    float4 b0 = {0,0,0,0}, b1 = b0, b2 = b0, b3 = b0;
    if (active) {
        int ct = tid & 31, wt = tid >> 5;
        c0 = ct * 4;
        w0 = wt * 4;
        b0 = *(const float4*)&ws[WS_BIAS + (c0 + 0) * 28 + w0];
        b1 = *(const float4*)&ws[WS_BIAS + (c0 + 1) * 28 + w0];
        b2 = *(const float4*)&ws[WS_BIAS + (c0 + 2) * 28 + w0];
        b3 = *(const float4*)&ws[WS_BIAS + (c0 + 3) * 28 + w0];
    }
    float st1[4] = {0, 0, 0, 0};
    float st2[4] = {0, 0, 0, 0};

    const float* xbase = x + (size_t)n * (CIN * TDIM * VV);
    float* obase = out + (size_t)n * (COUT * TDIM * VV);
    float* mbase = mid + ((size_t)n * NTILE + ttile) * (TT * COUT * VV);

    // Prologue: stage x(t0) into s_x, then stage2(t0).
    {
        const float* xb = xbase + (size_t)t0 * VV;
        for (int i = tid; i < 64 * 25; i += 256) {
            int cin = i / 25, v = i % 25;
            s_x[v * 68 + cin] = xb[cin * (TDIM * VV) + v];
        }
    }
    __syncthreads();   // tables + s_x(t0) ready

    // stage2(t0) -> s_y
    for (int task = tid; task < 336; task += 256) {
        int cint = task & 15, swt = task >> 4;
        int cin0 = cint * 4, sw0 = swt * 4;
        float4 a0 = {0, 0, 0, 0}, a1 = a0, a2 = a0, a3 = a0;
        #pragma unroll
        for (int v = 0; v < 25; ++v) {
            float4 xv = *(const float4*)&s_x[v * 68 + cin0];
            float4 av = *(const float4*)&s_ae[v * 84 + sw0];
            fma4(a0, xv.x, av);
            fma4(a1, xv.y, av);
            fma4(a2, xv.z, av);
            fma4(a3, xv.w, av);
        }
        int s = sw0 / 28, w = sw0 % 28;
        int yb = (s * 64 + cin0) * 28 + w;
        *(float4*)&s_y[yb]      = a0;
        *(float4*)&s_y[yb + 28] = a1;
        *(float4*)&s_y[yb + 56] = a2;
        *(float4*)&s_y[yb + 84] = a3;
    }
    __syncthreads();   // s_y(t0) ready

    for (int tt = 0; tt < TT; ++tt) {
        // ---------------- Phase C: stage3(tt) ∥ x(tt+1) prefetch ----------
        float xr[7];
        if (tt < TT - 1) {
            const float* xb = xbase + (size_t)(t0 + tt + 1) * VV;
            #pragma unroll
            for (int m = 0; m < 7; ++m) {
                int i = tid + 256 * m;
                if (i < 1600) {
                    int cin = i / 25, v = i - cin * 25;
                    xr[m] = xb[cin * (TDIM * VV) + v];
                }
            }
        }

        if (active) {
            float4 r0 = b0, r1 = b1, r2 = b2, r3 = b3;
            #pragma unroll
            for (int s = 0; s < 3; ++s) {
                int g = (s * 128 + c0) / 48;
                int yb = (s * 64 + g * 8) * 28 + w0;
                int wb = s * 8 * 128 + c0;
                #pragma unroll
                for (int jj = 0; jj < 8; ++jj) {
                    float4 wv = *(const float4*)&s_w[wb + jj * 128];
                    float4 yv = *(const float4*)&s_y[yb + jj * 28];
                    fma4(r0, wv.x, yv);
                    fma4(r1, wv.y, yv);
                    fma4(r2, wv.z, yv);
                    fma4(r3, wv.w, yv);
                }
            }
            float4 rr[4] = {r0, r1, r2, r3};
            #pragma unroll
            for (int a = 0; a < 4; ++a) {
                float4 v = rr[a];
                if (w0 < 24) {
                    st1[a] += v.x + v.y + v.z + v.w;
                    st2[a] += v.x * v.x + v.y * v.y + v.z * v.z + v.w * v.w;
                } else {
                    st1[a] += v.x;
                    st2[a] += v.x * v.x;
                }
            }
            if (PERM) {
                // mid[t][w][c]: register transpose -> float4 over c.
                // Lanes ct=0..31 cover one dense 512B w-row (full lines);
                // w0==24 row is likewise a dense float4 over c.
                float* mt = mbase + tt * (COUT * VV);
                *(float4*)&mt[(w0 + 0) * COUT + c0] =
                    make_float4(r0.x, r1.x, r2.x, r3.x);
                if (w0 < 24) {
                    *(float4*)&mt[(w0 + 1) * COUT + c0] =
                        make_float4(r0.y, r1.y, r2.y, r3.y);
                    *(float4*)&mt[(w0 + 2) * COUT + c0] =
                        make_float4(r0.z, r1.z, r2.z, r3.z);
                    *(float4*)&mt[(w0 + 3) * COUT + c0] =
                        make_float4(r0.w, r1.w, r2.w, r3.w);
                }
            } else {
                // fallback: direct final-layout stores (correctness path)
                float* ob = obase + (size_t)(t0 + tt) * VV;
                #pragma unroll
                for (int a = 0; a < 4; ++a) {
                    float4 v = rr[a];
                    float* row = ob + (size_t)(c0 + a) * (TDIM * VV) + w0;
                    row[0] = v.x;
                    if (w0 < 24) { row[1] = v.y; row[2] = v.z; row[3] = v.w; }
                }
            }
        }

        // Commit prefetched x (s_x free: stage2(tt) done last phase).
        if (tt < TT - 1) {
            #pragma unroll
            for (int m = 0; m < 7; ++m) {
                int i = tid + 256 * m;
                if (i < 1600) {
                    int cin = i / 25, v = i - cin * 25;
                    s_x[v * 68 + cin] = xr[m];
                }
            }
            __syncthreads();   // s_x(tt+1) ready; all s_y(tt) reads done

            // -------------- Phase D: stage2(tt+1) -------------------------
            for (int task = tid; task < 336; task += 256) {
                int cint = task & 15, swt = task >> 4;
                int cin0 = cint * 4, sw0 = swt * 4;
                float4 a0 = {0, 0, 0, 0}, a1 = a0, a2 = a0, a3 = a0;
                #pragma unroll
                for (int v = 0; v < 25; ++v) {
                    float4 xv = *(const float4*)&s_x[v * 68 + cin0];
                    float4 av = *(const float4*)&s_ae[v * 84 + sw0];
                    fma4(a0, xv.x, av);
                    fma4(a1, xv.y, av);
                    fma4(a2, xv.z, av);
                    fma4(a3, xv.w, av);
                }
                int s = sw0 / 28, w = sw0 % 28;
                int yb = (s * 64 + cin0) * 28 + w;
                *(float4*)&s_y[yb]      = a0;
                *(float4*)&s_y[yb + 28] = a1;
                *(float4*)&s_y[yb + 56] = a2;
                *(float4*)&s_y[yb + 84] = a3;
            }
            __syncthreads();   // s_y(tt+1) ready
        }
    }

    if (active) {
        #pragma unroll
        for (int a = 0; a < 4; ++a) {
            atomicAdd(&s_stats[c0 + a], st1[a]);
            atomicAdd(&s_stats[128 + c0 + a], st2[a]);
        }
    }
    __syncthreads();
    if (tid < 128) {
        float* st = ws + WS_STATS + xcd * 256;
        atomicAdd(&st[tid], s_stats[tid]);
        atomicAdd(&st[128 + tid], s_stats[128 + tid]);
    }
}

// ---------------------------------------------------------------------------
// Finalize: fold 8 striped accumulators -> per-channel scale/shift.
// ---------------------------------------------------------------------------
__global__ void finalize_kernel(const float* __restrict__ gamma,
                                const float* __restrict__ beta,
                                float* __restrict__ ws) {
    const int c = threadIdx.x;
    if (c < 128) {
        float s = 0.0f, q = 0.0f;
        for (int k = 0; k < 8; ++k) {
            s += ws[WS_STATS + k * 256 + c];
            q += ws[WS_STATS + k * 256 + 128 + c];
        }
        const float inv = 1.0f / (float)NTV;
        float mean = s * inv;
        float var = q * inv - mean * mean;
        float sc = gamma[c] * rsqrtf(var + 1e-5f);
        ws[WS_SCALE + c] = sc;
        ws[WS_SHIFT + c] = beta[c] - mean * sc;
    }
}

// ---------------------------------------------------------------------------
// norm_perm: fused BN-apply + transpose from mid[n][t][w][c] (correctness-
// verified in round 1). One block per (n, c-quad): aligned float4 gathers
// (4 channels per load), LDS deinterleave, coalesced float4 stores of 4
// contiguous (n,c) output planes. XCD-swizzled for L2 locality.
// ---------------------------------------------------------------------------
__global__ __launch_bounds__(256)
void norm_perm(const float* __restrict__ mid, float* __restrict__ out,
               const float* __restrict__ ws) {
    __shared__ __align__(16) float sb[4 * 1600];   // [cl][t64*25]
    const int tid = threadIdx.x;
    const int bid = blockIdx.x;
    const int xcd = bid & 7;
    const int j   = bid >> 3;           // [0,256)
    const int cq  = xcd * 4 + (j & 3);  // [0,32)
    const int n   = j >> 2;             // [0,64)
    const int c0  = cq * 4;

    float sca[4], sha[4];
    #pragma unroll
    for (int cl = 0; cl < 4; ++cl) {
        sca[cl] = ws[WS_SCALE + c0 + cl];
        sha[cl] = ws[WS_SHIFT + c0 + cl];
    }

    const float* mb = mid + (size_t)n * (TDIM * COUT * VV) + c0;
    for (int tc = 0; tc < 4; ++tc) {               // t-chunks of 64
        const float* mc = mb + (size_t)tc * 64 * (COUT * VV);
        #pragma unroll
        for (int k = 0; k < 7; ++k) {
            int idx = k * 256 + tid;               // (t*25 + w), t in [0,64)
            if (idx < 1600) {
                int t = idx / 25;
                int w = idx - t * 25;
                float4 v = *(const float4*)&mc[(size_t)t * (COUT * VV) + w * COUT];
                sb[idx]        = v.x;
                sb[1600 + idx] = v.y;
                sb[3200 + idx] = v.z;
                sb[4800 + idx] = v.w;
            }
        }
        __syncthreads();
        #pragma unroll
        for (int cl = 0; cl < 4; ++cl) {
            float4* ob = (float4*)out + ((size_t)(n * COUT + c0 + cl) * 1600 + tc * 400);
            const float4* sv = (const float4*)&sb[cl * 1600];
            #pragma unroll
            for (int k = 0; k < 2; ++k) {
                int idx = k * 256 + tid;
                if (idx < 400) {
                    float4 v = sv[idx];
                    v.x = fmaf(v.x, sca[cl], sha[cl]);
                    v.y = fmaf(v.y, sca[cl], sha[cl]);
                    v.z = fmaf(v.z, sca[cl], sha[cl]);
                    v.w = fmaf(v.w, sca[cl], sha[cl]);
                    ob[idx] = v;
                }
            }
        }
        __syncthreads();
    }
}

// ---------------------------------------------------------------------------
// Fallback: normalize d_out in place (used if ws too small for mid).
// ---------------------------------------------------------------------------
__global__ __launch_bounds__(256)
void norm_inplace(float* __restrict__ out, const float* __restrict__ ws) {
    const int total4 = OUT_TOTAL / 4;
    const int stride = gridDim.x * blockDim.x;
    for (int i = blockIdx.x * blockDim.x + threadIdx.x; i < total4; i += stride) {
        int c = (i / 1600) & 127;
        float sc = ws[WS_SCALE + c];
        float sh = ws[WS_SHIFT + c];
        float4 v = ((float4*)out)[i];
        v.x = fmaf(v.x, sc, sh);
        v.y = fmaf(v.y, sc, sh);
        v.z = fmaf(v.z, sc, sh);
        v.w = fmaf(v.w, sc, sh);
        ((float4*)out)[i] = v;
    }
}

extern "C" void kernel_launch(void* const* d_in, const int* in_sizes, int n_in,
                              void* d_out, int out_size, void* d_ws, size_t ws_size,
                              hipStream_t stream) {
    const float* x     = (const float*)d_in[0];
    const float* A     = (const float*)d_in[1];
    const float* PA    = (const float*)d_in[2];
    const float* Wg    = (const float*)d_in[3];
    const float* bg    = (const float*)d_in[4];
    const float* gamma = (const float*)d_in[5];
    const float* beta  = (const float*)d_in[6];
    float* out = (float*)d_out;
    float* ws  = (float*)d_ws;
    float* mid = ws + MID_OFF;

    // ws_size is constant across calls -> deterministic branch, graph-safe.
    const bool perm = ws_size >= ((size_t)MID_OFF + (size_t)OUT_TOTAL) * sizeof(float);

    prep_kernel<<<1, 256, 0, stream>>>(A, PA, Wg, bg, ws);
    if (perm) {
        main_kernel<true><<<NB * NTILE, 256, 0, stream>>>(x, ws, out, mid);
        finalize_kernel<<<1, 128, 0, stream>>>(gamma, beta, ws);
        norm_perm<<<NB * 32, 256, 0, stream>>>(mid, out, ws);
    } else {
        main_kernel<false><<<NB * NTILE, 256, 0, stream>>>(x, ws, out, mid);
        finalize_kernel<<<1, 128, 0, stream>>>(gamma, beta, ws);
        norm_inplace<<<4096, 256, 0, stream>>>(out, ws);
    }
}

// Round 7
// 1846.871 us; speedup vs baseline: 1.0543x; 1.0543x over previous
//
#include <hip/hip_runtime.h>
#include <math.h>

// Problem constants
#define NB   64
#define CIN  64
#define TDIM 256
#define VV   25
#define SS   3
#define COUT 128
#define NTV  (NB * TDIM * VV)              // 409600 elements per channel
#define OUT_TOTAL (NB * COUT * TDIM * VV)  // 52428800
#define TT   8                              // t per block
#define NTILE (TDIM / TT)                   // 32 t-tiles

// Workspace float offsets
#define WS_STATS 0        // 8 copies x (128 sum + 128 sumsq) = 2048 floats
#define WS_AE2   2048     // [25][84]: Aeff[s][v][w] laid out ae[v*84 + s*28 + w]
#define WS_W2    4160     // [24][128]: W2[(s*8+j)*128 + c] = Wg[(s*128+c)*8 + j]
#define WS_BIAS  7232     // [128][28]: bias_eff[c][w]
#define WS_SCALE 10816    // [128]
#define WS_SHIFT 10944    // [128]
#define MID_OFF  16384    // permuted intermediate: [n][ttile][tt][c*25+v], 52428800 floats

__device__ __forceinline__ void fma4(float4& a, float s, const float4& b) {
    a.x = fmaf(s, b.x, a.x);
    a.y = fmaf(s, b.y, a.y);
    a.z = fmaf(s, b.z, a.z);
    a.w = fmaf(s, b.w, a.w);
}

// ---------------------------------------------------------------------------
// Prep: build Aeff / W2 / bias_eff tables in ws, zero the stats accumulators.
// ---------------------------------------------------------------------------
__global__ void prep_kernel(const float* __restrict__ A, const float* __restrict__ PA,
                            const float* __restrict__ Wg, const float* __restrict__ bg,
                            float* __restrict__ ws) {
    const int tid = threadIdx.x;
    for (int i = tid; i < 2048; i += 256) ws[WS_STATS + i] = 0.0f;
    for (int i = tid; i < 25 * 84; i += 256) {
        int v = i / 84, r = i % 84;
        int s = r / 28, w = r % 28;
        float val = 0.0f;
        if (w < 25) {
            int idx = s * 625 + v * 25 + w;
            val = A[idx] + PA[idx];
        }
        ws[WS_AE2 + i] = val;
    }
    for (int i = tid; i < 24 * 128; i += 256) {
        int row = i / 128, c = i % 128;
        int s = row / 8, j = row % 8;
        ws[WS_W2 + i] = Wg[(s * 128 + c) * 8 + j];
    }
    for (int i = tid; i < 128 * 28; i += 256) {
        int c = i / 28, w = i % 28;
        float val = 0.0f;
        if (w < 25) {
            for (int s = 0; s < 3; ++s) {
                float cs = 0.0f;
                for (int v = 0; v < 25; ++v) {
                    int idx = s * 625 + v * 25 + w;
                    cs += A[idx] + PA[idx];
                }
                val += bg[s * 128 + c] * cs;
            }
        }
        ws[WS_BIAS + i] = val;
    }
}

// ---------------------------------------------------------------------------
// Main: one block per (n, 8-t tile), 512 THREADS (was 256). Identical data
// layouts, LDS buffers, schedule (round-3/5 verified 2-phase + s_res bounce);
// only the work partition changes: 2 blocks/CU x 8 waves = 4 waves/SIMD (2x
// latency hiding vs round 5's 2). Stage3: thread owns 2 channels x 4 w (s_y
// reads become wave-uniform broadcasts). Ledger: W2 in LDS (r2); mid written
// ONLY via the contiguous LDS-bounce float4 stream (r1,r4,r6: every
// register-direct store variant tripled HBM traffic).
// ---------------------------------------------------------------------------
template <bool PERM>
__global__ __launch_bounds__(512, 4)
void main_kernel(const float* __restrict__ x, float* __restrict__ ws,
                 float* __restrict__ out, float* __restrict__ mid) {
    __shared__ __align__(16) float s_x[25 * 68];     // xst[v][cin], pad 68
    __shared__ __align__(16) float s_ae[25 * 84];    // ae[v][s*28+w]
    __shared__ __align__(16) float s_w[24 * 128];    // W2[(s*8+j)][c]
    __shared__ __align__(16) float s_y[3 * 64 * 28]; // y[s][cin][w28]
    __shared__ __align__(16) float s_res[128 * 25];  // result bounce [c*25+w]
    __shared__ float s_stats[256];                   // 128 sum + 128 sumsq

    const int tid = threadIdx.x;
    const int bid = blockIdx.x;
    const int xcd   = bid & 7;           // dispatch round-robin heuristic
    const int j     = bid >> 3;          // [0,256)
    const int ttile = xcd * 4 + (j & 3); // [0,32): XCD k owns t-tiles [4k,4k+4)
    const int n     = j >> 2;            // [0,64)
    const int t0    = ttile * TT;

    if (tid < 256) s_stats[tid] = 0.0f;
    for (int i = tid; i < 25 * 84; i += 512) s_ae[i] = ws[WS_AE2 + i];
    for (int i = tid; i < 24 * 128; i += 512) s_w[i] = ws[WS_W2 + i];

    // stage3 mapping: ct = lane in [0,64) -> 2 channels; wt = wave -> 4 w.
    const int ct = tid & 63;
    const int wt = tid >> 6;            // wave index [0,8)
    const bool active = wt < 7;         // wave 7 idle in stage3
    const int c0 = ct * 2;
    const int w0 = wt * 4;
    float4 b0 = {0,0,0,0}, b1 = b0;
    if (active) {
        b0 = *(const float4*)&ws[WS_BIAS + (c0 + 0) * 28 + w0];
        b1 = *(const float4*)&ws[WS_BIAS + (c0 + 1) * 28 + w0];
    }
    float st1[2] = {0, 0};
    float st2[2] = {0, 0};

    const float* xbase = x + (size_t)n * (CIN * TDIM * VV);
    float* obase = out + (size_t)n * (COUT * TDIM * VV);
    float* mbase = mid + ((size_t)n * NTILE + ttile) * (TT * COUT * VV);

    // Prologue: stage x(t0) into s_x, then stage2(t0).
    {
        const float* xb = xbase + (size_t)t0 * VV;
        for (int i = tid; i < 64 * 25; i += 512) {
            int cin = i / 25, v = i % 25;
            s_x[v * 68 + cin] = xb[cin * (TDIM * VV) + v];
        }
    }
    __syncthreads();   // tables + s_x(t0) ready

    // stage2(t0) -> s_y: 336 tasks, one per thread (tid<336)
    if (tid < 336) {
        int cint = tid & 15, swt = tid >> 4;
        int cin0 = cint * 4, sw0 = swt * 4;
        float4 a0 = {0, 0, 0, 0}, a1 = a0, a2 = a0, a3 = a0;
        #pragma unroll
        for (int v = 0; v < 25; ++v) {
            float4 xv = *(const float4*)&s_x[v * 68 + cin0];
            float4 av = *(const float4*)&s_ae[v * 84 + sw0];
            fma4(a0, xv.x, av);
            fma4(a1, xv.y, av);
            fma4(a2, xv.z, av);
            fma4(a3, xv.w, av);
        }
        int s = sw0 / 28, w = sw0 % 28;
        int yb = (s * 64 + cin0) * 28 + w;
        *(float4*)&s_y[yb]      = a0;
        *(float4*)&s_y[yb + 28] = a1;
        *(float4*)&s_y[yb + 56] = a2;
        *(float4*)&s_y[yb + 84] = a3;
    }
    __syncthreads();   // s_y(t0) ready

    for (int tt = 0; tt < TT; ++tt) {
        // ---------------- Phase C: stage3(tt) ∥ x(tt+1) prefetch ----------
        // Issue next-t global loads first; latency hides under stage3.
        float xr[4];
        if (tt < TT - 1) {
            const float* xb = xbase + (size_t)(t0 + tt + 1) * VV;
            #pragma unroll
            for (int m = 0; m < 4; ++m) {
                int i = tid + 512 * m;
                if (i < 1600) {
                    int cin = i / 25, v = i - cin * 25;
                    xr[m] = xb[cin * (TDIM * VV) + v];
                }
            }
        }

        if (active) {
            float4 r0 = b0, r1 = b1;
            #pragma unroll
            for (int s = 0; s < 3; ++s) {
                int g = (s * 128 + c0) / 48;
                int yb = (s * 64 + g * 8) * 28 + w0;
                int wb = s * 8 * 128 + c0;
                #pragma unroll
                for (int jj = 0; jj < 8; ++jj) {
                    float2 wv = *(const float2*)&s_w[wb + jj * 128];
                    float4 yv = *(const float4*)&s_y[yb + jj * 28]; // wave-uniform
                    fma4(r0, wv.x, yv);
                    fma4(r1, wv.y, yv);
                }
            }
            float4 rr[2] = {r0, r1};
            #pragma unroll
            for (int a = 0; a < 2; ++a) {
                float4 v = rr[a];
                if (w0 < 24) {
                    st1[a] += v.x + v.y + v.z + v.w;
                    st2[a] += v.x * v.x + v.y * v.y + v.z * v.z + v.w * v.w;
                } else {
                    st1[a] += v.x;
                    st2[a] += v.x * v.x;
                }
            }
            #pragma unroll
            for (int a = 0; a < 2; ++a) {
                int base = (c0 + a) * 25 + w0;
                s_res[base] = rr[a].x;
                if (w0 < 24) {
                    s_res[base + 1] = rr[a].y;
                    s_res[base + 2] = rr[a].z;
                    s_res[base + 3] = rr[a].w;
                }
            }
        }

        // Commit prefetched x (s_x free: stage2(tt) finished last phase).
        if (tt < TT - 1) {
            #pragma unroll
            for (int m = 0; m < 4; ++m) {
                int i = tid + 512 * m;
                if (i < 1600) {
                    int cin = i / 25, v = i - cin * 25;
                    s_x[v * 68 + cin] = xr[m];
                }
            }
        }
        __syncthreads();   // s_res(tt) + s_x(tt+1) ready

        // ---------------- Phase D: copy s_res→mid ∥ stage2(tt+1) ----------
        if (PERM) {
            // Fully contiguous, 16B-aligned 12.8 KB stream per t -> no RFO
            float4* mb = (float4*)(mbase + tt * (COUT * VV));
            const float4* sr = (const float4*)s_res;
            for (int i = tid; i < 128 * 25 / 4; i += 512) mb[i] = sr[i];
        } else {
            float* ob = obase + (size_t)(t0 + tt) * VV;
            for (int i = tid; i < 128 * 25; i += 512) {
                int c = i / 25, w = i % 25;
                ob[c * (TDIM * VV) + w] = s_res[i];
            }
        }

        if (tt < TT - 1) {
            if (tid < 336) {
                int cint = tid & 15, swt = tid >> 4;
                int cin0 = cint * 4, sw0 = swt * 4;
                float4 a0 = {0, 0, 0, 0}, a1 = a0, a2 = a0, a3 = a0;
                #pragma unroll
                for (int v = 0; v < 25; ++v) {
                    float4 xv = *(const float4*)&s_x[v * 68 + cin0];
                    float4 av = *(const float4*)&s_ae[v * 84 + sw0];
                    fma4(a0, xv.x, av);
                    fma4(a1, xv.y, av);
                    fma4(a2, xv.z, av);
                    fma4(a3, xv.w, av);
                }
                int s = sw0 / 28, w = sw0 % 28;
                int yb = (s * 64 + cin0) * 28 + w;
                *(float4*)&s_y[yb]      = a0;
                *(float4*)&s_y[yb + 28] = a1;
                *(float4*)&s_y[yb + 56] = a2;
                *(float4*)&s_y[yb + 84] = a3;
            }
        }
        __syncthreads();   // s_y(tt+1) ready; s_res free for next phase C
    }

    if (active) {
        #pragma unroll
        for (int a = 0; a < 2; ++a) {
            atomicAdd(&s_stats[c0 + a], st1[a]);
            atomicAdd(&s_stats[128 + c0 + a], st2[a]);
        }
    }
    __syncthreads();
    if (tid < 128) {
        float* st = ws + WS_STATS + xcd * 256;
        atomicAdd(&st[tid], s_stats[tid]);
        atomicAdd(&st[128 + tid], s_stats[128 + tid]);
    }
}

// ---------------------------------------------------------------------------
// Finalize: fold 8 striped accumulators -> per-channel scale/shift.
// ---------------------------------------------------------------------------
__global__ void finalize_kernel(const float* __restrict__ gamma,
                                const float* __restrict__ beta,
                                float* __restrict__ ws) {
    const int c = threadIdx.x;
    if (c < 128) {
        float s = 0.0f, q = 0.0f;
        for (int k = 0; k < 8; ++k) {
            s += ws[WS_STATS + k * 256 + c];
            q += ws[WS_STATS + k * 256 + 128 + c];
        }
        const float inv = 1.0f / (float)NTV;
        float mean = s * inv;
        float var = q * inv - mean * mean;
        float sc = gamma[c] * rsqrtf(var + 1e-5f);
        ws[WS_SCALE + c] = sc;
        ws[WS_SHIFT + c] = beta[c] - mean * sc;
    }
}

// ---------------------------------------------------------------------------
// norm_perm: fused BN-apply + layout transpose, vectorized (verified r4/r5).
// One block per (n, c-quad): channels c0..c0+3 occupy 100 CONTIGUOUS
// 16B-aligned floats per t in mid -> float4-coalesced gathers, LDS transpose,
// float4-coalesced stores of 4 contiguous (n,c) output planes.
// ---------------------------------------------------------------------------
__global__ __launch_bounds__(256)
void norm_perm(const float* __restrict__ mid, float* __restrict__ out,
               const float* __restrict__ ws) {
    __shared__ __align__(16) float sb[6400];   // 64 t x [cl*25+v]
    const int tid = threadIdx.x;
    const int bid = blockIdx.x;
    const int n  = bid >> 5;            // [0,64)
    const int cq = bid & 31;            // [0,32)
    const int c0 = cq * 4;

    float sca[4], sha[4];
    #pragma unroll
    for (int cl = 0; cl < 4; ++cl) {
        sca[cl] = ws[WS_SCALE + c0 + cl];
        sha[cl] = ws[WS_SHIFT + c0 + cl];
    }

    const float* mb = mid + (size_t)n * (TDIM * COUT * VV) + c0 * VV;
    for (int tc = 0; tc < 4; ++tc) {               // t-chunks of 64
        const float* mc = mb + (size_t)tc * 64 * (COUT * VV);
        #pragma unroll
        for (int k = 0; k < 7; ++k) {
            int idx = k * 256 + tid;               // float4 index: t*25+q
            if (idx < 1600) {
                int t = idx / 25;
                int q = idx - t * 25;
                float4 v = *(const float4*)&mc[(size_t)t * (COUT * VV) + q * 4];
                *(float4*)&sb[idx * 4] = v;
            }
        }
        __syncthreads();
        #pragma unroll
        for (int cl = 0; cl < 4; ++cl) {
            float4* ob4 = (float4*)(out + ((size_t)(n * COUT + c0 + cl)) * (TDIM * VV)
                                        + tc * 1600);
            const float sc = sca[cl], sh = sha[cl];
            #pragma unroll
            for (int k = 0; k < 2; ++k) {
                int j4 = k * 256 + tid;
                if (j4 < 400) {
                    int jb = j4 * 4;
                    float4 r;
                    {
                        int t = (jb + 0) / 25, v = (jb + 0) - t * 25;
                        r.x = fmaf(sb[t * 100 + cl * 25 + v], sc, sh);
                    }
                    {
                        int t = (jb + 1) / 25, v = (jb + 1) - t * 25;
                        r.y = fmaf(sb[t * 100 + cl * 25 + v], sc, sh);
                    }
                    {
                        int t = (jb + 2) / 25, v = (jb + 2) - t * 25;
                        r.z = fmaf(sb[t * 100 + cl * 25 + v], sc, sh);
                    }
                    {
                        int t = (jb + 3) / 25, v = (jb + 3) - t * 25;
                        r.w = fmaf(sb[t * 100 + cl * 25 + v], sc, sh);
                    }
                    ob4[j4] = r;
                }
            }
        }
        __syncthreads();
    }
}

// ---------------------------------------------------------------------------
// Fallback: normalize d_out in place (used if ws too small for mid).
// ---------------------------------------------------------------------------
__global__ __launch_bounds__(256)
void norm_inplace(float* __restrict__ out, const float* __restrict__ ws) {
    const int total4 = OUT_TOTAL / 4;
    const int stride = gridDim.x * blockDim.x;
    for (int i = blockIdx.x * blockDim.x + threadIdx.x; i < total4; i += stride) {
        int c = (i / 1600) & 127;
        float sc = ws[WS_SCALE + c];
        float sh = ws[WS_SHIFT + c];
        float4 v = ((float4*)out)[i];
        v.x = fmaf(v.x, sc, sh);
        v.y = fmaf(v.y, sc, sh);
        v.z = fmaf(v.z, sc, sh);
        v.w = fmaf(v.w, sc, sh);
        ((float4*)out)[i] = v;
    }
}

extern "C" void kernel_launch(void* const* d_in, const int* in_sizes, int n_in,
                              void* d_out, int out_size, void* d_ws, size_t ws_size,
                              hipStream_t stream) {
    const float* x     = (const float*)d_in[0];
    const float* A     = (const float*)d_in[1];
    const float* PA    = (const float*)d_in[2];
    const float* Wg    = (const float*)d_in[3];
    const float* bg    = (const float*)d_in[4];
    const float* gamma = (const float*)d_in[5];
    const float* beta  = (const float*)d_in[6];
    float* out = (float*)d_out;
    float* ws  = (float*)d_ws;
    float* mid = ws + MID_OFF;

    // ws_size is constant across calls -> deterministic branch, graph-safe.
    const bool perm = ws_size >= ((size_t)MID_OFF + (size_t)OUT_TOTAL) * sizeof(float);

    prep_kernel<<<1, 256, 0, stream>>>(A, PA, Wg, bg, ws);
    if (perm) {
        main_kernel<true><<<NB * NTILE, 512, 0, stream>>>(x, ws, out, mid);
        finalize_kernel<<<1, 128, 0, stream>>>(gamma, beta, ws);
        norm_perm<<<NB * 32, 256, 0, stream>>>(mid, out, ws);
    } else {
        main_kernel<false><<<NB * NTILE, 512, 0, stream>>>(x, ws, out, mid);
        finalize_kernel<<<1, 128, 0, stream>>>(gamma, beta, ws);
        norm_inplace<<<4096, 256, 0, stream>>>(out, ws);
    }
}

// Round 8
// 1070.669 us; speedup vs baseline: 1.8187x; 1.7250x over previous
//
#include <hip/hip_runtime.h>
#include <math.h>

// Problem constants
#define NB   64
#define CIN  64
#define TDIM 256
#define VV   25
#define SS   3
#define COUT 128
#define NTV  (NB * TDIM * VV)              // 409600 elements per channel
#define OUT_TOTAL (NB * COUT * TDIM * VV)  // 52428800
#define TT   8                              // t per block
#define NTILE (TDIM / TT)                   // 32 t-tiles

// Workspace float offsets
#define WS_STATS 0        // 8 copies x (128 sum + 128 sumsq) = 2048 floats
#define WS_AE2   2048     // [25][84]: Aeff[s][v][w] laid out ae[v*84 + s*28 + w]
#define WS_W2    4160     // [24][128]: W2[(s*8+j)*128 + c] = Wg[(s*128+c)*8 + j]
#define WS_BIAS  7232     // [128][28]: bias_eff[c][w]
#define WS_SCALE 10816    // [128]
#define WS_SHIFT 10944    // [128]
#define MID_OFF  16384    // permuted intermediate: [n][ttile][tt][c*25+v], 52428800 floats

__device__ __forceinline__ void fma4(float4& a, float s, const float4& b) {
    a.x = fmaf(s, b.x, a.x);
    a.y = fmaf(s, b.y, a.y);
    a.z = fmaf(s, b.z, a.z);
    a.w = fmaf(s, b.w, a.w);
}

// ---------------------------------------------------------------------------
// Prep: build Aeff / W2 / bias_eff tables in ws, zero the stats accumulators.
// Parallelized across 64 blocks (was 1 block serializing ~8K scattered loads
// on a single CU). Identical arithmetic, disjoint grid-stride index ranges.
// ---------------------------------------------------------------------------
__global__ void prep_kernel(const float* __restrict__ A, const float* __restrict__ PA,
                            const float* __restrict__ Wg, const float* __restrict__ bg,
                            float* __restrict__ ws) {
    const int gid = blockIdx.x * 256 + threadIdx.x;
    const int gstride = gridDim.x * 256;
    for (int i = gid; i < 2048; i += gstride) ws[WS_STATS + i] = 0.0f;
    for (int i = gid; i < 25 * 84; i += gstride) {
        int v = i / 84, r = i % 84;
        int s = r / 28, w = r % 28;
        float val = 0.0f;
        if (w < 25) {
            int idx = s * 625 + v * 25 + w;
            val = A[idx] + PA[idx];
        }
        ws[WS_AE2 + i] = val;
    }
    for (int i = gid; i < 24 * 128; i += gstride) {
        int row = i / 128, c = i % 128;
        int s = row / 8, j = row % 8;
        ws[WS_W2 + i] = Wg[(s * 128 + c) * 8 + j];
    }
    for (int i = gid; i < 128 * 28; i += gstride) {
        int c = i / 28, w = i % 28;
        float val = 0.0f;
        if (w < 25) {
            for (int s = 0; s < 3; ++s) {
                float cs = 0.0f;
                for (int v = 0; v < 25; ++v) {
                    int idx = s * 625 + v * 25 + w;
                    cs += A[idx] + PA[idx];
                }
                val += bg[s * 128 + c] * cs;
            }
        }
        ws[WS_BIAS + i] = val;
    }
}

// ---------------------------------------------------------------------------
// Main: one block per (n, 8-t tile). Verified round-3/5 structure (765 us):
//   phase C: stage3(tt) [VALU] ∥ x(tt+1) prefetch -> s_res + s_x commit
//   phase D: s_res→mid full-line float4 stream ∥ stage2(tt+1)
// Ledger (hard rules, each violated->~2x regression):
//   - W2 must be LDS-resident (r2)
//   - mid written ONLY via contiguous LDS-bounce float4 stream (r1,r4,r6)
//   - this exact 256-thread partition only (r7: 512-thr repartition also
//     tripled FETCH+WRITE; mechanism undiagnosed — do not restructure)
// ---------------------------------------------------------------------------
template <bool PERM>
__global__ __launch_bounds__(256, 2)
void main_kernel(const float* __restrict__ x, float* __restrict__ ws,
                 float* __restrict__ out, float* __restrict__ mid) {
    __shared__ __align__(16) float s_x[25 * 68];     // xst[v][cin], pad 68
    __shared__ __align__(16) float s_ae[25 * 84];    // ae[v][s*28+w]
    __shared__ __align__(16) float s_w[24 * 128];    // W2[(s*8+j)][c]
    __shared__ __align__(16) float s_y[3 * 64 * 28]; // y[s][cin][w28]
    __shared__ __align__(16) float s_res[128 * 25];  // result bounce [c*25+w]
    __shared__ float s_stats[256];                   // 128 sum + 128 sumsq

    const int tid = threadIdx.x;
    const int bid = blockIdx.x;
    const int xcd   = bid & 7;           // dispatch round-robin heuristic
    const int j     = bid >> 3;          // [0,256)
    const int ttile = xcd * 4 + (j & 3); // [0,32): XCD k owns t-tiles [4k,4k+4)
    const int n     = j >> 2;            // [0,64)
    const int t0    = ttile * TT;

    s_stats[tid] = 0.0f;
    for (int i = tid; i < 25 * 84; i += 256) s_ae[i] = ws[WS_AE2 + i];
    for (int i = tid; i < 24 * 128; i += 256) s_w[i] = ws[WS_W2 + i];

    const bool active = tid < 224;
    int c0 = 0, w0 = 0;
    float4 b0 = {0,0,0,0}, b1 = b0, b2 = b0, b3 = b0;
    if (active) {
        int ct = tid & 31, wt = tid >> 5;
        c0 = ct * 4;
        w0 = wt * 4;
        b0 = *(const float4*)&ws[WS_BIAS + (c0 + 0) * 28 + w0];
        b1 = *(const float4*)&ws[WS_BIAS + (c0 + 1) * 28 + w0];
        b2 = *(const float4*)&ws[WS_BIAS + (c0 + 2) * 28 + w0];
        b3 = *(const float4*)&ws[WS_BIAS + (c0 + 3) * 28 + w0];
    }
    float st1[4] = {0, 0, 0, 0};
    float st2[4] = {0, 0, 0, 0};

    const float* xbase = x + (size_t)n * (CIN * TDIM * VV);
    float* obase = out + (size_t)n * (COUT * TDIM * VV);
    float* mbase = mid + ((size_t)n * NTILE + ttile) * (TT * COUT * VV);

    // Prologue: stage x(t0) into s_x (same scatter as round-0), then stage2(t0).
    {
        const float* xb = xbase + (size_t)t0 * VV;
        for (int i = tid; i < 64 * 25; i += 256) {
            int cin = i / 25, v = i % 25;
            s_x[v * 68 + cin] = xb[cin * (TDIM * VV) + v];
        }
    }
    __syncthreads();   // tables + s_x(t0) ready

    // stage2(t0) -> s_y
    for (int task = tid; task < 336; task += 256) {
        int cint = task & 15, swt = task >> 4;
        int cin0 = cint * 4, sw0 = swt * 4;
        float4 a0 = {0, 0, 0, 0}, a1 = a0, a2 = a0, a3 = a0;
        #pragma unroll
        for (int v = 0; v < 25; ++v) {
            float4 xv = *(const float4*)&s_x[v * 68 + cin0];
            float4 av = *(const float4*)&s_ae[v * 84 + sw0];
            fma4(a0, xv.x, av);
            fma4(a1, xv.y, av);
            fma4(a2, xv.z, av);
            fma4(a3, xv.w, av);
        }
        int s = sw0 / 28, w = sw0 % 28;
        int yb = (s * 64 + cin0) * 28 + w;
        *(float4*)&s_y[yb]      = a0;
        *(float4*)&s_y[yb + 28] = a1;
        *(float4*)&s_y[yb + 56] = a2;
        *(float4*)&s_y[yb + 84] = a3;
    }
    __syncthreads();   // s_y(t0) ready

    for (int tt = 0; tt < TT; ++tt) {
        // ---------------- Phase C: stage3(tt) ∥ x(tt+1) prefetch ----------
        // Issue next-t global loads first; their latency hides under stage3.
        float xr[7];
        if (tt < TT - 1) {
            const float* xb = xbase + (size_t)(t0 + tt + 1) * VV;
            #pragma unroll
            for (int m = 0; m < 7; ++m) {
                int i = tid + 256 * m;
                if (i < 1600) {
                    int cin = i / 25, v = i - cin * 25;
                    xr[m] = xb[cin * (TDIM * VV) + v];
                }
            }
        }

        if (active) {
            float4 r0 = b0, r1 = b1, r2 = b2, r3 = b3;
            #pragma unroll
            for (int s = 0; s < 3; ++s) {
                int g = (s * 128 + c0) / 48;
                int yb = (s * 64 + g * 8) * 28 + w0;
                int wb = s * 8 * 128 + c0;
                #pragma unroll
                for (int jj = 0; jj < 8; ++jj) {
                    float4 wv = *(const float4*)&s_w[wb + jj * 128];
                    float4 yv = *(const float4*)&s_y[yb + jj * 28];
                    fma4(r0, wv.x, yv);
                    fma4(r1, wv.y, yv);
                    fma4(r2, wv.z, yv);
                    fma4(r3, wv.w, yv);
                }
            }
            float4 rr[4] = {r0, r1, r2, r3};
            #pragma unroll
            for (int a = 0; a < 4; ++a) {
                float4 v = rr[a];
                if (w0 + 3 < 25) {
                    st1[a] += v.x + v.y + v.z + v.w;
                    st2[a] += v.x * v.x + v.y * v.y + v.z * v.z + v.w * v.w;
                } else {
                    st1[a] += v.x;
                    st2[a] += v.x * v.x;
                }
            }
            #pragma unroll
            for (int a = 0; a < 4; ++a) {
                int base = (c0 + a) * 25 + w0;
                s_res[base] = rr[a].x;
                if (w0 + 3 < 25) {
                    s_res[base + 1] = rr[a].y;
                    s_res[base + 2] = rr[a].z;
                    s_res[base + 3] = rr[a].w;
                }
            }
        }

        // Commit prefetched x (s_x free: stage2(tt) finished last phase).
        if (tt < TT - 1) {
            #pragma unroll
            for (int m = 0; m < 7; ++m) {
                int i = tid + 256 * m;
                if (i < 1600) {
                    int cin = i / 25, v = i - cin * 25;
                    s_x[v * 68 + cin] = xr[m];
                }
            }
        }
        __syncthreads();   // s_res(tt) + s_x(tt+1) ready

        // ---------------- Phase D: copy s_res→mid ∥ stage2(tt+1) ----------
        if (PERM) {
            // Fully contiguous, 16B-aligned 12.8 KB stream per t -> no RFO
            float4* mb = (float4*)(mbase + tt * (COUT * VV));
            const float4* sr = (const float4*)s_res;
            for (int i = tid; i < 128 * 25 / 4; i += 256) mb[i] = sr[i];
        } else {
            float* ob = obase + (size_t)(t0 + tt) * VV;
            for (int i = tid; i < 128 * 25; i += 256) {
                int c = i / 25, w = i % 25;
                ob[c * (TDIM * VV) + w] = s_res[i];
            }
        }

        if (tt < TT - 1) {
            for (int task = tid; task < 336; task += 256) {
                int cint = task & 15, swt = task >> 4;
                int cin0 = cint * 4, sw0 = swt * 4;
                float4 a0 = {0, 0, 0, 0}, a1 = a0, a2 = a0, a3 = a0;
                #pragma unroll
                for (int v = 0; v < 25; ++v) {
                    float4 xv = *(const float4*)&s_x[v * 68 + cin0];
                    float4 av = *(const float4*)&s_ae[v * 84 + sw0];
                    fma4(a0, xv.x, av);
                    fma4(a1, xv.y, av);
                    fma4(a2, xv.z, av);
                    fma4(a3, xv.w, av);
                }
                int s = sw0 / 28, w = sw0 % 28;
                int yb = (s * 64 + cin0) * 28 + w;
                *(float4*)&s_y[yb]      = a0;
                *(float4*)&s_y[yb + 28] = a1;
                *(float4*)&s_y[yb + 56] = a2;
                *(float4*)&s_y[yb + 84] = a3;
            }
        }
        __syncthreads();   // s_y(tt+1) ready; s_res free for next phase C
    }

    if (active) {
        #pragma unroll
        for (int a = 0; a < 4; ++a) {
            atomicAdd(&s_stats[c0 + a], st1[a]);
            atomicAdd(&s_stats[128 + c0 + a], st2[a]);
        }
    }
    __syncthreads();
    if (tid < 128) {
        float* st = ws + WS_STATS + xcd * 256;
        atomicAdd(&st[tid], s_stats[tid]);
        atomicAdd(&st[128 + tid], s_stats[128 + tid]);
    }
}

// ---------------------------------------------------------------------------
// Finalize: fold 8 striped accumulators -> per-channel scale/shift.
// ---------------------------------------------------------------------------
__global__ void finalize_kernel(const float* __restrict__ gamma,
                                const float* __restrict__ beta,
                                float* __restrict__ ws) {
    const int c = threadIdx.x;
    if (c < 128) {
        float s = 0.0f, q = 0.0f;
        for (int k = 0; k < 8; ++k) {
            s += ws[WS_STATS + k * 256 + c];
            q += ws[WS_STATS + k * 256 + 128 + c];
        }
        const float inv = 1.0f / (float)NTV;
        float mean = s * inv;
        float var = q * inv - mean * mean;
        float sc = gamma[c] * rsqrtf(var + 1e-5f);
        ws[WS_SCALE + c] = sc;
        ws[WS_SHIFT + c] = beta[c] - mean * sc;
    }
}

// ---------------------------------------------------------------------------
// norm_perm: fused BN-apply + layout transpose, vectorized (verified r4/r5).
// One block per (n, c-quad): channels c0..c0+3 occupy 100 CONTIGUOUS
// 16B-aligned floats per t in mid -> float4-coalesced gathers, LDS transpose,
// float4-coalesced stores of 4 contiguous (n,c) output planes.
// ---------------------------------------------------------------------------
__global__ __launch_bounds__(256)
void norm_perm(const float* __restrict__ mid, float* __restrict__ out,
               const float* __restrict__ ws) {
    __shared__ __align__(16) float sb[6400];   // 64 t x [cl*25+v]
    const int tid = threadIdx.x;
    const int bid = blockIdx.x;
    const int n  = bid >> 5;            // [0,64)
    const int cq = bid & 31;            // [0,32)
    const int c0 = cq * 4;

    float sca[4], sha[4];
    #pragma unroll
    for (int cl = 0; cl < 4; ++cl) {
        sca[cl] = ws[WS_SCALE + c0 + cl];
        sha[cl] = ws[WS_SHIFT + c0 + cl];
    }

    const float* mb = mid + (size_t)n * (TDIM * COUT * VV) + c0 * VV;
    for (int tc = 0; tc < 4; ++tc) {               // t-chunks of 64
        const float* mc = mb + (size_t)tc * 64 * (COUT * VV);
        #pragma unroll
        for (int k = 0; k < 7; ++k) {
            int idx = k * 256 + tid;               // float4 index: t*25+q
            if (idx < 1600) {
                int t = idx / 25;
                int q = idx - t * 25;
                float4 v = *(const float4*)&mc[(size_t)t * (COUT * VV) + q * 4];
                *(float4*)&sb[idx * 4] = v;
            }
        }
        __syncthreads();
        #pragma unroll
        for (int cl = 0; cl < 4; ++cl) {
            float4* ob4 = (float4*)(out + ((size_t)(n * COUT + c0 + cl)) * (TDIM * VV)
                                        + tc * 1600);
            const float sc = sca[cl], sh = sha[cl];
            #pragma unroll
            for (int k = 0; k < 2; ++k) {
                int j4 = k * 256 + tid;
                if (j4 < 400) {
                    int jb = j4 * 4;
                    float4 r;
                    {
                        int t = (jb + 0) / 25, v = (jb + 0) - t * 25;
                        r.x = fmaf(sb[t * 100 + cl * 25 + v], sc, sh);
                    }
                    {
                        int t = (jb + 1) / 25, v = (jb + 1) - t * 25;
                        r.y = fmaf(sb[t * 100 + cl * 25 + v], sc, sh);
                    }
                    {
                        int t = (jb + 2) / 25, v = (jb + 2) - t * 25;
                        r.z = fmaf(sb[t * 100 + cl * 25 + v], sc, sh);
                    }
                    {
                        int t = (jb + 3) / 25, v = (jb + 3) - t * 25;
                        r.w = fmaf(sb[t * 100 + cl * 25 + v], sc, sh);
                    }
                    ob4[j4] = r;
                }
            }
        }
        __syncthreads();
    }
}

// ---------------------------------------------------------------------------
// Fallback: normalize d_out in place (used if ws too small for mid).
// ---------------------------------------------------------------------------
__global__ __launch_bounds__(256)
void norm_inplace(float* __restrict__ out, const float* __restrict__ ws) {
    const int total4 = OUT_TOTAL / 4;
    const int stride = gridDim.x * blockDim.x;
    for (int i = blockIdx.x * blockDim.x + threadIdx.x; i < total4; i += stride) {
        int c = (i / 1600) & 127;
        float sc = ws[WS_SCALE + c];
        float sh = ws[WS_SHIFT + c];
        float4 v = ((float4*)out)[i];
        v.x = fmaf(v.x, sc, sh);
        v.y = fmaf(v.y, sc, sh);
        v.z = fmaf(v.z, sc, sh);
        v.w = fmaf(v.w, sc, sh);
        ((float4*)out)[i] = v;
    }
}

extern "C" void kernel_launch(void* const* d_in, const int* in_sizes, int n_in,
                              void* d_out, int out_size, void* d_ws, size_t ws_size,
                              hipStream_t stream) {
    const float* x     = (const float*)d_in[0];
    const float* A     = (const float*)d_in[1];
    const float* PA    = (const float*)d_in[2];
    const float* Wg    = (const float*)d_in[3];
    const float* bg    = (const float*)d_in[4];
    const float* gamma = (const float*)d_in[5];
    const float* beta  = (const float*)d_in[6];
    float* out = (float*)d_out;
    float* ws  = (float*)d_ws;
    float* mid = ws + MID_OFF;

    // ws_size is constant across calls -> deterministic branch, graph-safe.
    const bool perm = ws_size >= ((size_t)MID_OFF + (size_t)OUT_TOTAL) * sizeof(float);

    prep_kernel<<<64, 256, 0, stream>>>(A, PA, Wg, bg, ws);
    if (perm) {
        main_kernel<true><<<NB * NTILE, 256, 0, stream>>>(x, ws, out, mid);
        finalize_kernel<<<1, 128, 0, stream>>>(gamma, beta, ws);
        norm_perm<<<NB * 32, 256, 0, stream>>>(mid, out, ws);
    } else {
        main_kernel<false><<<NB * NTILE, 256, 0, stream>>>(x, ws, out, mid);
        finalize_kernel<<<1, 128, 0, stream>>>(gamma, beta, ws);
        norm_inplace<<<4096, 256, 0, stream>>>(out, ws);
    }
}

// Round 9
// 1067.193 us; speedup vs baseline: 1.8246x; 1.0033x over previous
//
#include <hip/hip_runtime.h>
#include <math.h>

// Problem constants
#define NB   64
#define CIN  64
#define TDIM 256
#define VV   25
#define SS   3
#define COUT 128
#define NTV  (NB * TDIM * VV)              // 409600 elements per channel
#define OUT_TOTAL (NB * COUT * TDIM * VV)  // 52428800
#define TT   8                              // t per block
#define NTILE (TDIM / TT)                   // 32 t-tiles

// Workspace float offsets
#define WS_STATS 0        // 8 copies x (128 sum + 128 sumsq) = 2048 floats
#define WS_AE2   2048     // [25][84]: Aeff[s][v][w] laid out ae[v*84 + s*28 + w]
#define WS_W2    4160     // [24][128]: W2[(s*8+j)*128 + c] = Wg[(s*128+c)*8 + j]
#define WS_BIAS  7232     // [128][28]: bias_eff[c][w]
#define WS_SCALE 10816    // [128]
#define WS_SHIFT 10944    // [128]
#define MID_OFF  16384    // permuted intermediate: [n][ttile][tt][c*25+v], 52428800 floats

__device__ __forceinline__ void fma4(float4& a, float s, const float4& b) {
    a.x = fmaf(s, b.x, a.x);
    a.y = fmaf(s, b.y, a.y);
    a.z = fmaf(s, b.z, a.z);
    a.w = fmaf(s, b.w, a.w);
}

// ---------------------------------------------------------------------------
// Prep: build Aeff / W2 / bias_eff tables in ws, zero the stats accumulators.
// Grid-stride across 64 blocks (verified round 8).
// ---------------------------------------------------------------------------
__global__ void prep_kernel(const float* __restrict__ A, const float* __restrict__ PA,
                            const float* __restrict__ Wg, const float* __restrict__ bg,
                            float* __restrict__ ws) {
    const int gid = blockIdx.x * 256 + threadIdx.x;
    const int gstride = gridDim.x * 256;
    for (int i = gid; i < 2048; i += gstride) ws[WS_STATS + i] = 0.0f;
    for (int i = gid; i < 25 * 84; i += gstride) {
        int v = i / 84, r = i % 84;
        int s = r / 28, w = r % 28;
        float val = 0.0f;
        if (w < 25) {
            int idx = s * 625 + v * 25 + w;
            val = A[idx] + PA[idx];
        }
        ws[WS_AE2 + i] = val;
    }
    for (int i = gid; i < 24 * 128; i += gstride) {
        int row = i / 128, c = i % 128;
        int s = row / 8, j = row % 8;
        ws[WS_W2 + i] = Wg[(s * 128 + c) * 8 + j];
    }
    for (int i = gid; i < 128 * 28; i += gstride) {
        int c = i / 28, w = i % 28;
        float val = 0.0f;
        if (w < 25) {
            for (int s = 0; s < 3; ++s) {
                float cs = 0.0f;
                for (int v = 0; v < 25; ++v) {
                    int idx = s * 625 + v * 25 + w;
                    cs += A[idx] + PA[idx];
                }
                val += bg[s * 128 + c] * cs;
            }
        }
        ws[WS_BIAS + i] = val;
    }
}

// ---------------------------------------------------------------------------
// Main: one block per (n, 8-t tile). Verified round-3/5/8 structure (~770 us):
//   phase C: stage3(tt) [VALU] ∥ x(tt+1) prefetch -> s_res + s_x commit
//   phase D: s_res→mid full-line float4 stream ∥ stage2(tt+1)
// Ledger (hard rules, each violated->~2x regression):
//   - W2 must be LDS-resident (r2)
//   - mid written ONLY via contiguous LDS-bounce float4 stream (r1,r4,r6)
//   - this exact 256-thread partition only (r7)
// DO NOT RESTRUCTURE THIS KERNEL.
// ---------------------------------------------------------------------------
template <bool PERM>
__global__ __launch_bounds__(256, 2)
void main_kernel(const float* __restrict__ x, float* __restrict__ ws,
                 float* __restrict__ out, float* __restrict__ mid) {
    __shared__ __align__(16) float s_x[25 * 68];     // xst[v][cin], pad 68
    __shared__ __align__(16) float s_ae[25 * 84];    // ae[v][s*28+w]
    __shared__ __align__(16) float s_w[24 * 128];    // W2[(s*8+j)][c]
    __shared__ __align__(16) float s_y[3 * 64 * 28]; // y[s][cin][w28]
    __shared__ __align__(16) float s_res[128 * 25];  // result bounce [c*25+w]
    __shared__ float s_stats[256];                   // 128 sum + 128 sumsq

    const int tid = threadIdx.x;
    const int bid = blockIdx.x;
    const int xcd   = bid & 7;           // dispatch round-robin heuristic
    const int j     = bid >> 3;          // [0,256)
    const int ttile = xcd * 4 + (j & 3); // [0,32): XCD k owns t-tiles [4k,4k+4)
    const int n     = j >> 2;            // [0,64)
    const int t0    = ttile * TT;

    s_stats[tid] = 0.0f;
    for (int i = tid; i < 25 * 84; i += 256) s_ae[i] = ws[WS_AE2 + i];
    for (int i = tid; i < 24 * 128; i += 256) s_w[i] = ws[WS_W2 + i];

    const bool active = tid < 224;
    int c0 = 0, w0 = 0;
    float4 b0 = {0,0,0,0}, b1 = b0, b2 = b0, b3 = b0;
    if (active) {
        int ct = tid & 31, wt = tid >> 5;
        c0 = ct * 4;
        w0 = wt * 4;
        b0 = *(const float4*)&ws[WS_BIAS + (c0 + 0) * 28 + w0];
        b1 = *(const float4*)&ws[WS_BIAS + (c0 + 1) * 28 + w0];
        b2 = *(const float4*)&ws[WS_BIAS + (c0 + 2) * 28 + w0];
        b3 = *(const float4*)&ws[WS_BIAS + (c0 + 3) * 28 + w0];
    }
    float st1[4] = {0, 0, 0, 0};
    float st2[4] = {0, 0, 0, 0};

    const float* xbase = x + (size_t)n * (CIN * TDIM * VV);
    float* obase = out + (size_t)n * (COUT * TDIM * VV);
    float* mbase = mid + ((size_t)n * NTILE + ttile) * (TT * COUT * VV);

    // Prologue: stage x(t0) into s_x, then stage2(t0).
    {
        const float* xb = xbase + (size_t)t0 * VV;
        for (int i = tid; i < 64 * 25; i += 256) {
            int cin = i / 25, v = i % 25;
            s_x[v * 68 + cin] = xb[cin * (TDIM * VV) + v];
        }
    }
    __syncthreads();   // tables + s_x(t0) ready

    // stage2(t0) -> s_y
    for (int task = tid; task < 336; task += 256) {
        int cint = task & 15, swt = task >> 4;
        int cin0 = cint * 4, sw0 = swt * 4;
        float4 a0 = {0, 0, 0, 0}, a1 = a0, a2 = a0, a3 = a0;
        #pragma unroll
        for (int v = 0; v < 25; ++v) {
            float4 xv = *(const float4*)&s_x[v * 68 + cin0];
            float4 av = *(const float4*)&s_ae[v * 84 + sw0];
            fma4(a0, xv.x, av);
            fma4(a1, xv.y, av);
            fma4(a2, xv.z, av);
            fma4(a3, xv.w, av);
        }
        int s = sw0 / 28, w = sw0 % 28;
        int yb = (s * 64 + cin0) * 28 + w;
        *(float4*)&s_y[yb]      = a0;
        *(float4*)&s_y[yb + 28] = a1;
        *(float4*)&s_y[yb + 56] = a2;
        *(float4*)&s_y[yb + 84] = a3;
    }
    __syncthreads();   // s_y(t0) ready

    for (int tt = 0; tt < TT; ++tt) {
        // ---------------- Phase C: stage3(tt) ∥ x(tt+1) prefetch ----------
        float xr[7];
        if (tt < TT - 1) {
            const float* xb = xbase + (size_t)(t0 + tt + 1) * VV;
            #pragma unroll
            for (int m = 0; m < 7; ++m) {
                int i = tid + 256 * m;
                if (i < 1600) {
                    int cin = i / 25, v = i - cin * 25;
                    xr[m] = xb[cin * (TDIM * VV) + v];
                }
            }
        }

        if (active) {
            float4 r0 = b0, r1 = b1, r2 = b2, r3 = b3;
            #pragma unroll
            for (int s = 0; s < 3; ++s) {
                int g = (s * 128 + c0) / 48;
                int yb = (s * 64 + g * 8) * 28 + w0;
                int wb = s * 8 * 128 + c0;
                #pragma unroll
                for (int jj = 0; jj < 8; ++jj) {
                    float4 wv = *(const float4*)&s_w[wb + jj * 128];
                    float4 yv = *(const float4*)&s_y[yb + jj * 28];
                    fma4(r0, wv.x, yv);
                    fma4(r1, wv.y, yv);
                    fma4(r2, wv.z, yv);
                    fma4(r3, wv.w, yv);
                }
            }
            float4 rr[4] = {r0, r1, r2, r3};
            #pragma unroll
            for (int a = 0; a < 4; ++a) {
                float4 v = rr[a];
                if (w0 + 3 < 25) {
                    st1[a] += v.x + v.y + v.z + v.w;
                    st2[a] += v.x * v.x + v.y * v.y + v.z * v.z + v.w * v.w;
                } else {
                    st1[a] += v.x;
                    st2[a] += v.x * v.x;
                }
            }
            #pragma unroll
            for (int a = 0; a < 4; ++a) {
                int base = (c0 + a) * 25 + w0;
                s_res[base] = rr[a].x;
                if (w0 + 3 < 25) {
                    s_res[base + 1] = rr[a].y;
                    s_res[base + 2] = rr[a].z;
                    s_res[base + 3] = rr[a].w;
                }
            }
        }

        // Commit prefetched x (s_x free: stage2(tt) finished last phase).
        if (tt < TT - 1) {
            #pragma unroll
            for (int m = 0; m < 7; ++m) {
                int i = tid + 256 * m;
                if (i < 1600) {
                    int cin = i / 25, v = i - cin * 25;
                    s_x[v * 68 + cin] = xr[m];
                }
            }
        }
        __syncthreads();   // s_res(tt) + s_x(tt+1) ready

        // ---------------- Phase D: copy s_res→mid ∥ stage2(tt+1) ----------
        if (PERM) {
            float4* mb = (float4*)(mbase + tt * (COUT * VV));
            const float4* sr = (const float4*)s_res;
            for (int i = tid; i < 128 * 25 / 4; i += 256) mb[i] = sr[i];
        } else {
            float* ob = obase + (size_t)(t0 + tt) * VV;
            for (int i = tid; i < 128 * 25; i += 256) {
                int c = i / 25, w = i % 25;
                ob[c * (TDIM * VV) + w] = s_res[i];
            }
        }

        if (tt < TT - 1) {
            for (int task = tid; task < 336; task += 256) {
                int cint = task & 15, swt = task >> 4;
                int cin0 = cint * 4, sw0 = swt * 4;
                float4 a0 = {0, 0, 0, 0}, a1 = a0, a2 = a0, a3 = a0;
                #pragma unroll
                for (int v = 0; v < 25; ++v) {
                    float4 xv = *(const float4*)&s_x[v * 68 + cin0];
                    float4 av = *(const float4*)&s_ae[v * 84 + sw0];
                    fma4(a0, xv.x, av);
                    fma4(a1, xv.y, av);
                    fma4(a2, xv.z, av);
                    fma4(a3, xv.w, av);
                }
                int s = sw0 / 28, w = sw0 % 28;
                int yb = (s * 64 + cin0) * 28 + w;
                *(float4*)&s_y[yb]      = a0;
                *(float4*)&s_y[yb + 28] = a1;
                *(float4*)&s_y[yb + 56] = a2;
                *(float4*)&s_y[yb + 84] = a3;
            }
        }
        __syncthreads();   // s_y(tt+1) ready; s_res free for next phase C
    }

    if (active) {
        #pragma unroll
        for (int a = 0; a < 4; ++a) {
            atomicAdd(&s_stats[c0 + a], st1[a]);
            atomicAdd(&s_stats[128 + c0 + a], st2[a]);
        }
    }
    __syncthreads();
    if (tid < 128) {
        float* st = ws + WS_STATS + xcd * 256;
        atomicAdd(&st[tid], s_stats[tid]);
        atomicAdd(&st[128 + tid], s_stats[128 + tid]);
    }
}

// ---------------------------------------------------------------------------
// Finalize: fold 8 striped accumulators -> per-channel scale/shift.
// (Only used by the norm_inplace fallback path; the perm path inlines this.)
// ---------------------------------------------------------------------------
__global__ void finalize_kernel(const float* __restrict__ gamma,
                                const float* __restrict__ beta,
                                float* __restrict__ ws) {
    const int c = threadIdx.x;
    if (c < 128) {
        float s = 0.0f, q = 0.0f;
        for (int k = 0; k < 8; ++k) {
            s += ws[WS_STATS + k * 256 + c];
            q += ws[WS_STATS + k * 256 + 128 + c];
        }
        const float inv = 1.0f / (float)NTV;
        float mean = s * inv;
        float var = q * inv - mean * mean;
        float sc = gamma[c] * rsqrtf(var + 1e-5f);
        ws[WS_SCALE + c] = sc;
        ws[WS_SHIFT + c] = beta[c] - mean * sc;
    }
}

// ---------------------------------------------------------------------------
// norm_perm: fused stats-finalize + BN-apply + layout transpose. One block
// per (n, c-quad, t-chunk): 8192 blocks, single load-phase + barrier +
// store-phase (was 4 sequential chunks x 2 barriers in 2048 blocks). Each
// block folds the 8-stripe stats for its 4 channels inline (deterministic,
// stats complete at kernel boundary) -> no separate finalize dispatch.
// ---------------------------------------------------------------------------
__global__ __launch_bounds__(256)
void norm_perm(const float* __restrict__ mid, float* __restrict__ out,
               const float* __restrict__ ws,
               const float* __restrict__ gamma, const float* __restrict__ beta) {
    __shared__ __align__(16) float sb[6400];   // 64 t x [cl*25+v]
    const int tid = threadIdx.x;
    const int bid = blockIdx.x;
    const int n  = bid >> 7;            // [0,64)
    const int r  = bid & 127;
    const int cq = r >> 2;              // [0,32)
    const int tc = r & 3;               // [0,4)
    const int c0 = cq * 4;

    float sca[4], sha[4];
    #pragma unroll
    for (int cl = 0; cl < 4; ++cl) {
        const int c = c0 + cl;
        float s = 0.0f, q = 0.0f;
        #pragma unroll
        for (int k = 0; k < 8; ++k) {
            s += ws[WS_STATS + k * 256 + c];
            q += ws[WS_STATS + k * 256 + 128 + c];
        }
        const float inv = 1.0f / (float)NTV;
        float mean = s * inv;
        float var = q * inv - mean * mean;
        float sc = gamma[c] * rsqrtf(var + 1e-5f);
        sca[cl] = sc;
        sha[cl] = beta[c] - mean * sc;
    }

    const float* mc = mid + (size_t)n * (TDIM * COUT * VV) + c0 * VV
                          + (size_t)tc * 64 * (COUT * VV);
    #pragma unroll
    for (int k = 0; k < 7; ++k) {
        int idx = k * 256 + tid;               // float4 index: t*25+q
        if (idx < 1600) {
            int t = idx / 25;
            int q = idx - t * 25;
            float4 v = *(const float4*)&mc[(size_t)t * (COUT * VV) + q * 4];
            *(float4*)&sb[idx * 4] = v;
        }
    }
    __syncthreads();
    #pragma unroll
    for (int cl = 0; cl < 4; ++cl) {
        float4* ob4 = (float4*)(out + ((size_t)(n * COUT + c0 + cl)) * (TDIM * VV)
                                    + tc * 1600);
        const float sc = sca[cl], sh = sha[cl];
        #pragma unroll
        for (int k = 0; k < 2; ++k) {
            int j4 = k * 256 + tid;
            if (j4 < 400) {
                int jb = j4 * 4;
                float4 rv;
                {
                    int t = (jb + 0) / 25, v = (jb + 0) - t * 25;
                    rv.x = fmaf(sb[t * 100 + cl * 25 + v], sc, sh);
                }
                {
                    int t = (jb + 1) / 25, v = (jb + 1) - t * 25;
                    rv.y = fmaf(sb[t * 100 + cl * 25 + v], sc, sh);
                }
                {
                    int t = (jb + 2) / 25, v = (jb + 2) - t * 25;
                    rv.z = fmaf(sb[t * 100 + cl * 25 + v], sc, sh);
                }
                {
                    int t = (jb + 3) / 25, v = (jb + 3) - t * 25;
                    rv.w = fmaf(sb[t * 100 + cl * 25 + v], sc, sh);
                }
                ob4[j4] = rv;
            }
        }
    }
}

// ---------------------------------------------------------------------------
// Fallback: normalize d_out in place (used if ws too small for mid).
// ---------------------------------------------------------------------------
__global__ __launch_bounds__(256)
void norm_inplace(float* __restrict__ out, const float* __restrict__ ws) {
    const int total4 = OUT_TOTAL / 4;
    const int stride = gridDim.x * blockDim.x;
    for (int i = blockIdx.x * blockDim.x + threadIdx.x; i < total4; i += stride) {
        int c = (i / 1600) & 127;
        float sc = ws[WS_SCALE + c];
        float sh = ws[WS_SHIFT + c];
        float4 v = ((float4*)out)[i];
        v.x = fmaf(v.x, sc, sh);
        v.y = fmaf(v.y, sc, sh);
        v.z = fmaf(v.z, sc, sh);
        v.w = fmaf(v.w, sc, sh);
        ((float4*)out)[i] = v;
    }
}

extern "C" void kernel_launch(void* const* d_in, const int* in_sizes, int n_in,
                              void* d_out, int out_size, void* d_ws, size_t ws_size,
                              hipStream_t stream) {
    const float* x     = (const float*)d_in[0];
    const float* A     = (const float*)d_in[1];
    const float* PA    = (const float*)d_in[2];
    const float* Wg    = (const float*)d_in[3];
    const float* bg    = (const float*)d_in[4];
    const float* gamma = (const float*)d_in[5];
    const float* beta  = (const float*)d_in[6];
    float* out = (float*)d_out;
    float* ws  = (float*)d_ws;
    float* mid = ws + MID_OFF;

    // ws_size is constant across calls -> deterministic branch, graph-safe.
    const bool perm = ws_size >= ((size_t)MID_OFF + (size_t)OUT_TOTAL) * sizeof(float);

    prep_kernel<<<64, 256, 0, stream>>>(A, PA, Wg, bg, ws);
    if (perm) {
        main_kernel<true><<<NB * NTILE, 256, 0, stream>>>(x, ws, out, mid);
        norm_perm<<<NB * 128, 256, 0, stream>>>(mid, out, ws, gamma, beta);
    } else {
        main_kernel<false><<<NB * NTILE, 256, 0, stream>>>(x, ws, out, mid);
        finalize_kernel<<<1, 128, 0, stream>>>(gamma, beta, ws);
        norm_inplace<<<4096, 256, 0, stream>>>(out, ws);
    }
}